// Round 8
// baseline (24.866 us; speedup 1.0000x reference)
//
#include <hip/hip_runtime.h>
#include <hip/hip_bf16.h>

#define BB 64
#define SS 512
#define HH 1024
#define LL 9

// DPP row_shr shift-add: after ctrl {1,2,4,8}, lane 15 of each 16-lane row
// holds the sum of all 16 lanes. VALU-rate, no LDS pipe. (verified R2-R7)
template <int CTRL>
__device__ __forceinline__ float dpp_add(float v) {
    int s = __builtin_bit_cast(int, v);
    int r = __builtin_amdgcn_update_dpp(0, s, CTRL, 0xF, 0xF, true);
    return v + __builtin_bit_cast(float, r);
}

// Fused NER head, R8: exact static partition, 2 blocks/CU.
// 512 blocks x 256 threads (4 waves). Block (bat=blockIdx&63, blk=blockIdx>>6)
// computes valid-queue slice [blk*nv/8, (blk+1)*nv/8) of its batch (<=64 rows,
// imbalance <=1 row; no mirror heuristic, no second pass) and fills its slice
// of pad rows with softmax(bias). 4 rows per 16-lane group (halves LDS W-reads
// vs R7). 43 KB LDS -> 2 independent blocks/CU (decorrelated phases).
__global__ __launch_bounds__(256) void fused_ner_kernel(
    const float* __restrict__ x, const int* __restrict__ mask,
    const float* __restrict__ W, const float* __restrict__ bias,
    float* __restrict__ out) {
    __shared__ __align__(16) float Wl[HH * LL];  // 36 KB, row-major W[h][l]
    __shared__ int gidx_sh[SS];
    __shared__ int wsum[4];
    __shared__ float bsh[LL];
    __shared__ float obuf[64 * LL];              // this block's <=64 valid rows

    const int tid  = threadIdx.x;
    const int bat  = blockIdx.x & 63;
    const int blk  = blockIdx.x >> 6;            // 0..7: slice index
    const int lane = tid & 63;
    const int wv_  = tid >> 6;                   // wave 0..3

    // ---- async stage W (row-major): 2304 float4, 9 per thread ----
    #pragma unroll
    for (int i = 0; i < 9; ++i) {
        const int f4 = i * 256 + tid;
        __builtin_amdgcn_global_load_lds(
            (const __attribute__((address_space(1))) void*)(W + f4 * 4),
            (__attribute__((address_space(3))) void*)(&Wl[f4 * 4]),
            16, 0, 0);
    }
    if (tid < LL) bsh[tid] = bias[tid];

    // ---- stable-compaction scan: 256 threads, 2 tokens each ----
    const int2 mm = reinterpret_cast<const int2*>(mask + bat * SS)[tid];
    const int m0 = mm.x, m1 = mm.y;
    const int s = m0 + m1;
    int incl = s;
    #pragma unroll
    for (int off = 1; off < 64; off <<= 1) {
        int u = __shfl_up(incl, off, 64);
        if (lane >= off) incl += u;
    }
    if (lane == 63) wsum[wv_] = incl;
    __syncthreads();                             // wsum ready; W stage drained
    int wbase = 0;
    #pragma unroll
    for (int i = 0; i < 4; ++i) if (i < wv_) wbase += wsum[i];
    const int nv = wsum[0] + wsum[1] + wsum[2] + wsum[3];
    const int excl = incl - s + wbase;
    if (m0) gidx_sh[excl] = 2 * tid;
    if (m1) gidx_sh[excl + m0] = 2 * tid + 1;
    __syncthreads();                             // gidx_sh readable

    // ---- this block's exact slices ----
    const int jbeg = (blk * nv) >> 3;            // valid-queue slice
    const int jend = ((blk + 1) * nv) >> 3;
    const int nwork = jend - jbeg;               // <= 64
    const int npad = SS - nv;
    const int pbeg = nv + ((blk * npad) >> 3);   // pad slice
    const int pend = nv + (((blk + 1) * npad) >> 3);

    // ---- gather-GEMM: 16-lane group computes 4 queue rows ----
    const int g = lane >> 4;                     // group 0..3 (== DPP row)
    const int k = lane & 15;
    const int G = wv_ * 4 + g;                   // 0..15

    float acc[4][LL];
    #pragma unroll
    for (int r = 0; r < 4; ++r)
        #pragma unroll
        for (int l = 0; l < LL; ++l) acc[r][l] = 0.f;

    float sc[4];
    const float4* xr[4];
    #pragma unroll
    for (int r = 0; r < 4; ++r) {
        const int j = jbeg + G * 4 + r;          // queue position
        const bool valid = (j < jend);
        sc[r] = valid ? 1.f : 0.f;
        const int src = valid ? gidx_sh[j] : 0;  // never deref garbage
        xr[r] = reinterpret_cast<const float4*>(x + ((size_t)bat * SS + src) * HH);
    }

    if (G * 4 < nwork || (g == 0 && wv_ == 0 && nwork > 0)) { /* see below */ }
    if (wv_ * 16 < nwork) {                      // wave-uniform: any real work?
        float4 xv[4][4];                         // [slot][row] prefetch ring
        #pragma unroll
        for (int c = 0; c < 3; ++c)
            #pragma unroll
            for (int r = 0; r < 4; ++r) xv[c][r] = xr[r][c * 16 + k];

        #pragma unroll 4
        for (int c = 0; c < 16; ++c) {
            const int nc = (c + 3) & 15;         // wrap: tail reloads (L1-hit)
            #pragma unroll
            for (int r = 0; r < 4; ++r) xv[nc & 3][r] = xr[r][nc * 16 + k];

            // lane's 4x9 W sub-block: 36 contiguous floats, 9 ds_read_b128
            float4 wb[9];
            const float* wp = &Wl[(c * 16 + k) * 36];
            #pragma unroll
            for (int j2 = 0; j2 < 9; ++j2)
                wb[j2] = *reinterpret_cast<const float4*>(wp + j2 * 4);
            const float* wf = reinterpret_cast<const float*>(wb); // wf[dh*9+l]

            #pragma unroll
            for (int l = 0; l < LL; ++l) {
                #pragma unroll
                for (int r = 0; r < 4; ++r) {
                    const float4 xvv = xv[c & 3][r];
                    acc[r][l] += xvv.x * wf[0 * 9 + l] + xvv.y * wf[1 * 9 + l]
                               + xvv.z * wf[2 * 9 + l] + xvv.w * wf[3 * 9 + l];
                }
            }
        }
        // reduce across the 16-lane group; lane k==15 holds each total
        #pragma unroll
        for (int r = 0; r < 4; ++r)
            #pragma unroll
            for (int l = 0; l < LL; ++l) {
                float v = acc[r][l];
                v = dpp_add<0x111>(v);
                v = dpp_add<0x112>(v);
                v = dpp_add<0x114>(v);
                v = dpp_add<0x118>(v);
                acc[r][l] = v;
            }

        if (k == 15) {
            #pragma unroll
            for (int r = 0; r < 4; ++r) {
                float lg[LL];
                float mx = -3.0e38f;
                #pragma unroll
                for (int l = 0; l < LL; ++l) {
                    lg[l] = acc[r][l] * sc[r] + bsh[l];
                    mx = fmaxf(mx, lg[l]);
                }
                float ssum = 0.f;
                #pragma unroll
                for (int l = 0; l < LL; ++l) { lg[l] = __expf(lg[l] - mx); ssum += lg[l]; }
                const float inv = 1.f / ssum;
                const int lp = G * 4 + r;        // 0..63
                #pragma unroll
                for (int l = 0; l < LL; ++l) obuf[lp * LL + l] = lg[l] * inv;
            }
        }
    }

    // softmax(bias) in registers (for pad slice)
    float bs[LL];
    float mxb = -3.0e38f;
    #pragma unroll
    for (int l = 0; l < LL; ++l) { bs[l] = bsh[l]; mxb = fmaxf(mxb, bs[l]); }
    float sb = 0.f;
    #pragma unroll
    for (int l = 0; l < LL; ++l) { bs[l] = __expf(bs[l] - mxb); sb += bs[l]; }
    const float invb = 1.f / sb;

    __syncthreads();                             // obuf complete

    // valid slice: contiguous nwork*9 floats
    const size_t vbase = ((size_t)bat * SS + jbeg) * LL;
    for (int t = tid; t < nwork * LL; t += 256) out[vbase + t] = obuf[t];

    // pad slice: contiguous (pend-pbeg)*9 floats of softmax(bias)
    const size_t pbase = ((size_t)bat * SS + pbeg) * LL;
    const int pn = (pend - pbeg) * LL;
    for (int t = tid; t < pn; t += 256) {
        const int row = t / LL;                  // const-div -> magic mul
        const int l   = t - row * LL;
        out[pbase + t] = bs[l] * invb;
    }
}

extern "C" void kernel_launch(void* const* d_in, const int* in_sizes, int n_in,
                              void* d_out, int out_size, void* d_ws, size_t ws_size,
                              hipStream_t stream) {
    const float* x    = (const float*)d_in[0];   // [B,S,H] f32
    const int*   mask = (const int*)d_in[1];     // [B,S] i32
    const float* W    = (const float*)d_in[2];   // [H,L] f32
    const float* bias = (const float*)d_in[3];   // [L] f32
    float* out = (float*)d_out;                  // [B,S,L] f32

    fused_ner_kernel<<<BB * 8, 256, 0, stream>>>(x, mask, W, bias, out);
}

// Round 9
// 24.142 us; speedup vs baseline: 1.0300x; 1.0300x over previous
//
#include <hip/hip_runtime.h>
#include <hip/hip_bf16.h>

#define BB 64
#define SS 512
#define HH 1024
#define LL 9

// DPP row_shr shift-add: after ctrl {1,2,4,8}, lane 15 of each 16-lane row
// holds the sum of all 16 lanes. VALU-rate, no LDS pipe. (verified R2-R8)
template <int CTRL>
__device__ __forceinline__ float dpp_add(float v) {
    int s = __builtin_bit_cast(int, v);
    int r = __builtin_amdgcn_update_dpp(0, s, CTRL, 0xF, 0xF, true);
    return v + __builtin_bit_cast(float, r);
}

// R9: full-wave row reads with burst prefetch.
// 512 blocks x 256 threads (4 waves), R8's exact static partition.
// Per job, a wave owns 4 queue rows and issues ALL 16 x-loads up front:
// 4 rows x 4 chunks x 1KB contiguous per wave-instruction = 16KB in flight
// per wave (~5x R8's ring) -> Little's-law coverage of HBM latency.
// W read from LDS per i-chunk: lane needs h-block (i*64+lane)'s 36 floats
// (9 ds_read_b128); 36KB per 4-row job == R8's LDS traffic (unchanged).
__global__ __launch_bounds__(256) void fused_ner_kernel(
    const float* __restrict__ x, const int* __restrict__ mask,
    const float* __restrict__ W, const float* __restrict__ bias,
    float* __restrict__ out) {
    __shared__ __align__(16) float Wl[HH * LL];  // 36 KB, row-major W[h][l]
    __shared__ int gidx_sh[SS];
    __shared__ int wsum[4];
    __shared__ float bsh[LL];
    __shared__ float obuf[64 * LL];

    const int tid  = threadIdx.x;
    const int bat  = blockIdx.x & 63;
    const int blk  = blockIdx.x >> 6;            // 0..7: slice index
    const int lane = tid & 63;
    const int wv_  = tid >> 6;                   // wave 0..3

    // ---- async stage W (row-major): 2304 float4, 9 per thread ----
    #pragma unroll
    for (int i = 0; i < 9; ++i) {
        const int f4 = i * 256 + tid;
        __builtin_amdgcn_global_load_lds(
            (const __attribute__((address_space(1))) void*)(W + f4 * 4),
            (__attribute__((address_space(3))) void*)(&Wl[f4 * 4]),
            16, 0, 0);
    }
    if (tid < LL) bsh[tid] = bias[tid];

    // ---- stable-compaction scan: 256 threads, 2 tokens each ----
    const int2 mm = reinterpret_cast<const int2*>(mask + bat * SS)[tid];
    const int m0 = mm.x, m1 = mm.y;
    const int s = m0 + m1;
    int incl = s;
    #pragma unroll
    for (int off = 1; off < 64; off <<= 1) {
        int u = __shfl_up(incl, off, 64);
        if (lane >= off) incl += u;
    }
    if (lane == 63) wsum[wv_] = incl;
    __syncthreads();                             // wsum ready; W stage drained
    int wbase = 0;
    #pragma unroll
    for (int i = 0; i < 4; ++i) if (i < wv_) wbase += wsum[i];
    const int nv = wsum[0] + wsum[1] + wsum[2] + wsum[3];
    const int excl = incl - s + wbase;
    if (m0) gidx_sh[excl] = 2 * tid;
    if (m1) gidx_sh[excl + m0] = 2 * tid + 1;
    __syncthreads();                             // gidx_sh readable

    // ---- this block's exact slices ----
    const int jbeg = (blk * nv) >> 3;
    const int jend = ((blk + 1) * nv) >> 3;
    const int nwork = jend - jbeg;               // <= 64
    const int npad = SS - nv;
    const int pbeg = nv + ((blk * npad) >> 3);
    const int pend = nv + (((blk + 1) * npad) >> 3);

    const int g = lane >> 4;                     // group 0..3
    const int k = lane & 15;

    // ---- jobs: wave takes 4 queue rows per pass ----
    #pragma unroll 1
    for (int pass = 0; pass < 4; ++pass) {
        const int lp0 = pass * 16 + wv_ * 4;     // local row base (this wave)
        if (lp0 >= nwork) break;                 // wave-uniform

        float sc[4];
        const float4* xr[4];
        #pragma unroll
        for (int r = 0; r < 4; ++r) {
            const int j = jbeg + lp0 + r;
            const bool valid = (j < jend);
            sc[r] = valid ? 1.f : 0.f;
            const int src = gidx_sh[valid ? j : jbeg];  // jbeg valid (nwork>0)
            xr[r] = reinterpret_cast<const float4*>(x + ((size_t)bat * SS + src) * HH);
        }

        // burst: issue all 16 wave-loads (1KB contiguous each) up front
        float4 xq[4][4];                         // [r][i], static-indexed
        #pragma unroll
        for (int i = 0; i < 4; ++i)
            #pragma unroll
            for (int r = 0; r < 4; ++r) xq[r][i] = xr[r][i * 64 + lane];

        float acc[4][LL];
        #pragma unroll
        for (int r = 0; r < 4; ++r)
            #pragma unroll
            for (int l = 0; l < LL; ++l) acc[r][l] = 0.f;

        #pragma unroll
        for (int i = 0; i < 4; ++i) {
            // lane's W sub-block for h-block (i*64+lane): 36 contiguous floats
            float4 wb[9];
            const float* wp = &Wl[(i * 64 + lane) * 36];
            #pragma unroll
            for (int j2 = 0; j2 < 9; ++j2)
                wb[j2] = *reinterpret_cast<const float4*>(wp + j2 * 4);
            const float* wf = reinterpret_cast<const float*>(wb); // wf[dh*9+l]

            #pragma unroll
            for (int l = 0; l < LL; ++l) {
                #pragma unroll
                for (int r = 0; r < 4; ++r) {
                    const float4 xvv = xq[r][i];
                    acc[r][l] += xvv.x * wf[0 * 9 + l] + xvv.y * wf[1 * 9 + l]
                               + xvv.z * wf[2 * 9 + l] + xvv.w * wf[3 * 9 + l];
                }
            }
        }

        // reduce across 64 lanes: 4 DPP steps (within 16) + xor 16/32 across
        // groups (k==15 lanes exchange with k==15 lanes). After this, every
        // k==15 lane holds full totals for all 4 rows.
        #pragma unroll
        for (int r = 0; r < 4; ++r)
            #pragma unroll
            for (int l = 0; l < LL; ++l) {
                float v = acc[r][l];
                v = dpp_add<0x111>(v);
                v = dpp_add<0x112>(v);
                v = dpp_add<0x114>(v);
                v = dpp_add<0x118>(v);
                v += __shfl_xor(v, 16, 64);
                v += __shfl_xor(v, 32, 64);
                acc[r][l] = v;
            }

        // lane (g, k==15) handles row g: select statically (no dyn reg index)
        float lg[LL];
        #pragma unroll
        for (int l = 0; l < LL; ++l) {
            float v = acc[0][l] * sc[0];
            if (g == 1) v = acc[1][l] * sc[1];
            if (g == 2) v = acc[2][l] * sc[2];
            if (g == 3) v = acc[3][l] * sc[3];
            lg[l] = v + bsh[l];
        }
        float mx = -3.0e38f;
        #pragma unroll
        for (int l = 0; l < LL; ++l) mx = fmaxf(mx, lg[l]);
        float ssum = 0.f;
        #pragma unroll
        for (int l = 0; l < LL; ++l) { lg[l] = __expf(lg[l] - mx); ssum += lg[l]; }
        const float inv = 1.f / ssum;
        if (k == 15) {
            #pragma unroll
            for (int l = 0; l < LL; ++l) obuf[(lp0 + g) * LL + l] = lg[l] * inv;
        }
    }

    // softmax(bias) in registers (for pad slice)
    float bs[LL];
    float mxb = -3.0e38f;
    #pragma unroll
    for (int l = 0; l < LL; ++l) { bs[l] = bsh[l]; mxb = fmaxf(mxb, bs[l]); }
    float sb = 0.f;
    #pragma unroll
    for (int l = 0; l < LL; ++l) { bs[l] = __expf(bs[l] - mxb); sb += bs[l]; }
    const float invb = 1.f / sb;

    __syncthreads();                             // obuf complete

    // valid slice: contiguous nwork*9 floats
    const size_t vbase = ((size_t)bat * SS + jbeg) * LL;
    for (int t = tid; t < nwork * LL; t += 256) out[vbase + t] = obuf[t];

    // pad slice: contiguous (pend-pbeg)*9 floats of softmax(bias)
    const size_t pbase = ((size_t)bat * SS + pbeg) * LL;
    const int pn = (pend - pbeg) * LL;
    for (int t = tid; t < pn; t += 256) {
        const int row = t / LL;
        const int l   = t - row * LL;
        out[pbase + t] = bs[l] * invb;
    }
}

extern "C" void kernel_launch(void* const* d_in, const int* in_sizes, int n_in,
                              void* d_out, int out_size, void* d_ws, size_t ws_size,
                              hipStream_t stream) {
    const float* x    = (const float*)d_in[0];   // [B,S,H] f32
    const int*   mask = (const int*)d_in[1];     // [B,S] i32
    const float* W    = (const float*)d_in[2];   // [H,L] f32
    const float* bias = (const float*)d_in[3];   // [L] f32
    float* out = (float*)d_out;                  // [B,S,L] f32

    fused_ner_kernel<<<BB * 8, 256, 0, stream>>>(x, mask, W, bias, out);
}

// Round 10
// 22.756 us; speedup vs baseline: 1.0927x; 1.0609x over previous
//
#include <hip/hip_runtime.h>
#include <hip/hip_bf16.h>

#define BB 64
#define SS 512
#define HH 1024
#define LL 9

// DPP add helper: ctrl 0x111/0x112/0x114/0x118 = row_shr 1/2/4/8 (within
// 16-lane rows); 0x142 = row_bcast15, 0x143 = row_bcast31 (cross-row).
// Sequence shr1,2,4,8 + bcast15 + bcast31 leaves the full 64-lane sum in
// lane 63. All VALU-rate, zero LDS pipe. (row_shr path verified R2-R9)
template <int CTRL>
__device__ __forceinline__ float dpp_add(float v) {
    int s = __builtin_bit_cast(int, v);
    int r = __builtin_amdgcn_update_dpp(0, s, CTRL, 0xF, 0xF, true);
    return v + __builtin_bit_cast(float, r);
}

// R10: main loop touches ONLY VMEM + VALU.
// 512 blocks x 256 threads (4 waves), exact static partition (R8).
// W held in 144 VGPRs per lane (lane's 4 fixed h-blocks), loaded from LDS
// once per block. Reduce = 6 DPP adds (no shfl/bpermute). 2 rows per wave
// per pass, all 16 1KB wave-loads of a pass issued back-to-back.
__global__ __launch_bounds__(256, 2) void fused_ner_kernel(
    const float* __restrict__ x, const int* __restrict__ mask,
    const float* __restrict__ W, const float* __restrict__ bias,
    float* __restrict__ out) {
    __shared__ __align__(16) float Wl[HH * LL];  // 36 KB, row-major W[h][l]
    __shared__ int gidx_sh[SS];
    __shared__ int wsum[4];
    __shared__ float bsh[LL];
    __shared__ float obuf[64 * LL];

    const int tid  = threadIdx.x;
    const int bat  = blockIdx.x & 63;
    const int blk  = blockIdx.x >> 6;            // 0..7: slice index
    const int lane = tid & 63;
    const int wv_  = tid >> 6;                   // wave 0..3

    // ---- async stage W (row-major): 2304 float4, 9 per thread ----
    #pragma unroll
    for (int i = 0; i < 9; ++i) {
        const int f4 = i * 256 + tid;
        __builtin_amdgcn_global_load_lds(
            (const __attribute__((address_space(1))) void*)(W + f4 * 4),
            (__attribute__((address_space(3))) void*)(&Wl[f4 * 4]),
            16, 0, 0);
    }
    if (tid < LL) bsh[tid] = bias[tid];

    // ---- stable-compaction scan: 256 threads, 2 tokens each ----
    const int2 mm = reinterpret_cast<const int2*>(mask + bat * SS)[tid];
    const int m0 = mm.x, m1 = mm.y;
    const int s = m0 + m1;
    int incl = s;
    #pragma unroll
    for (int off = 1; off < 64; off <<= 1) {
        int u = __shfl_up(incl, off, 64);
        if (lane >= off) incl += u;
    }
    if (lane == 63) wsum[wv_] = incl;
    __syncthreads();                             // wsum ready; W stage drained
    int wbase = 0;
    #pragma unroll
    for (int i = 0; i < 4; ++i) if (i < wv_) wbase += wsum[i];
    const int nv = wsum[0] + wsum[1] + wsum[2] + wsum[3];
    const int excl = incl - s + wbase;
    if (m0) gidx_sh[excl] = 2 * tid;
    if (m1) gidx_sh[excl + m0] = 2 * tid + 1;
    __syncthreads();                             // gidx_sh + Wl readable

    // ---- hoist W into registers: lane's 4 h-blocks are pass-invariant ----
    // wf[i][dh*9+l] = W[(i*64+lane)*4 + dh][l]; 144 VGPRs, static-indexed.
    float wf[4][36];
    #pragma unroll
    for (int i = 0; i < 4; ++i) {
        const float* wp = &Wl[(i * 64 + lane) * 36];
        #pragma unroll
        for (int j = 0; j < 9; ++j) {
            const float4 t = *reinterpret_cast<const float4*>(wp + j * 4);
            wf[i][j * 4 + 0] = t.x;
            wf[i][j * 4 + 1] = t.y;
            wf[i][j * 4 + 2] = t.z;
            wf[i][j * 4 + 3] = t.w;
        }
    }

    // ---- this block's exact slices ----
    const int jbeg = (blk * nv) >> 3;
    const int jend = ((blk + 1) * nv) >> 3;
    const int nwork = jend - jbeg;               // <= 64
    const int npad = SS - nv;
    const int pbeg = nv + ((blk * npad) >> 3);
    const int pend = nv + (((blk + 1) * npad) >> 3);

    // ---- pass loop: wave computes 2 queue rows per pass, pure VMEM+VALU ----
    #pragma unroll 1
    for (int pass = 0; pass < 8; ++pass) {
        const int lp0 = pass * 8 + wv_ * 2;      // local row base (this wave)
        if (lp0 >= nwork) break;                 // wave-uniform

        float sc[2];
        const float4* xr[2];
        #pragma unroll
        for (int r = 0; r < 2; ++r) {
            const int j = jbeg + lp0 + r;
            const bool valid = (j < jend);
            sc[r] = valid ? 1.f : 0.f;
            const int src = gidx_sh[valid ? j : jbeg];   // jbeg valid (nwork>0)
            xr[r] = reinterpret_cast<const float4*>(x + ((size_t)bat * SS + src) * HH);
        }

        // burst: 8 wave-loads (1KB contiguous each) issued back-to-back
        float4 xq[2][4];                         // [r][i], static-indexed
        #pragma unroll
        for (int i = 0; i < 4; ++i)
            #pragma unroll
            for (int r = 0; r < 2; ++r) xq[r][i] = xr[r][i * 64 + lane];

        float acc[2][LL];
        #pragma unroll
        for (int r = 0; r < 2; ++r)
            #pragma unroll
            for (int l = 0; l < LL; ++l) acc[r][l] = 0.f;

        #pragma unroll
        for (int i = 0; i < 4; ++i) {
            #pragma unroll
            for (int l = 0; l < LL; ++l) {
                #pragma unroll
                for (int r = 0; r < 2; ++r) {
                    const float4 xvv = xq[r][i];
                    acc[r][l] += xvv.x * wf[i][0 * 9 + l] + xvv.y * wf[i][1 * 9 + l]
                               + xvv.z * wf[i][2 * 9 + l] + xvv.w * wf[i][3 * 9 + l];
                }
            }
        }

        // 64-lane reduce, pure DPP: lane 63 ends with each full total
        #pragma unroll
        for (int r = 0; r < 2; ++r)
            #pragma unroll
            for (int l = 0; l < LL; ++l) {
                float v = acc[r][l];
                v = dpp_add<0x111>(v);           // row_shr:1
                v = dpp_add<0x112>(v);           // row_shr:2
                v = dpp_add<0x114>(v);           // row_shr:4
                v = dpp_add<0x118>(v);           // row_shr:8
                v = dpp_add<0x142>(v);           // row_bcast15
                v = dpp_add<0x143>(v);           // row_bcast31
                acc[r][l] = v;
            }

        if (lane == 63) {
            #pragma unroll
            for (int r = 0; r < 2; ++r) {
                float lg[LL];
                float mx = -3.0e38f;
                #pragma unroll
                for (int l = 0; l < LL; ++l) {
                    lg[l] = acc[r][l] * sc[r] + bsh[l];
                    mx = fmaxf(mx, lg[l]);
                }
                float ssum = 0.f;
                #pragma unroll
                for (int l = 0; l < LL; ++l) { lg[l] = __expf(lg[l] - mx); ssum += lg[l]; }
                const float inv = 1.f / ssum;
                #pragma unroll
                for (int l = 0; l < LL; ++l) obuf[(lp0 + r) * LL + l] = lg[l] * inv;
            }
        }
    }

    // softmax(bias) in registers (for pad slice)
    float bs[LL];
    float mxb = -3.0e38f;
    #pragma unroll
    for (int l = 0; l < LL; ++l) { bs[l] = bsh[l]; mxb = fmaxf(mxb, bs[l]); }
    float sb = 0.f;
    #pragma unroll
    for (int l = 0; l < LL; ++l) { bs[l] = __expf(bs[l] - mxb); sb += bs[l]; }
    const float invb = 1.f / sb;

    __syncthreads();                             // obuf complete

    // valid slice: contiguous nwork*9 floats
    const size_t vbase = ((size_t)bat * SS + jbeg) * LL;
    for (int t = tid; t < nwork * LL; t += 256) out[vbase + t] = obuf[t];

    // pad slice: contiguous (pend-pbeg)*9 floats of softmax(bias)
    const size_t pbase = ((size_t)bat * SS + pbeg) * LL;
    const int pn = (pend - pbeg) * LL;
    for (int t = tid; t < pn; t += 256) {
        const int row = t / LL;
        const int l   = t - row * LL;
        out[pbase + t] = bs[l] * invb;
    }
}

extern "C" void kernel_launch(void* const* d_in, const int* in_sizes, int n_in,
                              void* d_out, int out_size, void* d_ws, size_t ws_size,
                              hipStream_t stream) {
    const float* x    = (const float*)d_in[0];   // [B,S,H] f32
    const int*   mask = (const int*)d_in[1];     // [B,S] i32
    const float* W    = (const float*)d_in[2];   // [H,L] f32
    const float* bias = (const float*)d_in[3];   // [L] f32
    float* out = (float*)d_out;                  // [B,S,L] f32

    fused_ner_kernel<<<BB * 8, 256, 0, stream>>>(x, mask, W, bias, out);
}

// Round 11
// 22.555 us; speedup vs baseline: 1.1025x; 1.0089x over previous
//
#include <hip/hip_runtime.h>
#include <hip/hip_bf16.h>

#define BB 64
#define SS 512
#define HH 1024
#define LL 9

// DPP add helper: 0x111/0x112/0x114/0x118 = row_shr 1/2/4/8;
// 0x142 = row_bcast15, 0x143 = row_bcast31. Sequence leaves the full
// 64-lane sum in lane 63. All VALU-rate, zero LDS pipe. (verified R10)
template <int CTRL>
__device__ __forceinline__ float dpp_add(float v) {
    int s = __builtin_bit_cast(int, v);
    int r = __builtin_amdgcn_update_dpp(0, s, CTRL, 0xF, 0xF, true);
    return v + __builtin_bit_cast(float, r);
}

// R11: occupancy over per-wave depth. 1024 blocks (64 batches x 16 exact
// slices) x 256 threads. __launch_bounds__(256,4) caps VGPR<=128 and LDS
// ~38KB -> 4 blocks/CU = 16 waves/CU (2x R10). W read from LDS per chunk
// (overlaps VMEM stalls on the LDS pipe); 2 rows per wave-pass, 8 1KB
// wave-loads issued back-to-back per pass.
__global__ __launch_bounds__(256, 4) void fused_ner_kernel(
    const float* __restrict__ x, const int* __restrict__ mask,
    const float* __restrict__ W, const float* __restrict__ bias,
    float* __restrict__ out) {
    __shared__ __align__(16) float Wl[HH * LL];   // 36 KB, row-major W[h][l]
    __shared__ unsigned short gidx_sh[SS];        // 1 KB (ushort: fits LDS cap)
    __shared__ int wsum[4];
    __shared__ float bsh[LL];
    __shared__ float obuf[32 * LL];               // slice <= 32 valid rows

    const int tid  = threadIdx.x;
    const int bat  = blockIdx.x & 63;             // consecutive -> XCD spread
    const int blk  = blockIdx.x >> 6;             // 0..15: slice index
    const int lane = tid & 63;
    const int wv_  = tid >> 6;                    // wave 0..3

    // ---- async stage W (row-major): 2304 float4, 9 per thread ----
    #pragma unroll
    for (int i = 0; i < 9; ++i) {
        const int f4 = i * 256 + tid;
        __builtin_amdgcn_global_load_lds(
            (const __attribute__((address_space(1))) void*)(W + f4 * 4),
            (__attribute__((address_space(3))) void*)(&Wl[f4 * 4]),
            16, 0, 0);
    }
    if (tid < LL) bsh[tid] = bias[tid];

    // ---- stable-compaction scan: 256 threads, 2 tokens each ----
    const int2 mm = reinterpret_cast<const int2*>(mask + bat * SS)[tid];
    const int m0 = mm.x, m1 = mm.y;
    const int s = m0 + m1;
    int incl = s;
    #pragma unroll
    for (int off = 1; off < 64; off <<= 1) {
        int u = __shfl_up(incl, off, 64);
        if (lane >= off) incl += u;
    }
    if (lane == 63) wsum[wv_] = incl;
    __syncthreads();                              // wsum ready; W stage drained
    int wbase = 0;
    #pragma unroll
    for (int i = 0; i < 4; ++i) if (i < wv_) wbase += wsum[i];
    const int nv = wsum[0] + wsum[1] + wsum[2] + wsum[3];
    const int excl = incl - s + wbase;
    if (m0) gidx_sh[excl] = (unsigned short)(2 * tid);
    if (m1) gidx_sh[excl + m0] = (unsigned short)(2 * tid + 1);
    __syncthreads();                              // gidx_sh + Wl readable

    // ---- this block's exact slices (16 per batch) ----
    const int jbeg = (blk * nv) >> 4;
    const int jend = ((blk + 1) * nv) >> 4;
    const int nwork = jend - jbeg;                // <= 32
    const int npad = SS - nv;
    const int pbeg = nv + ((blk * npad) >> 4);
    const int pend = nv + (((blk + 1) * npad) >> 4);

    // ---- pass loop: wave computes 2 queue rows per pass ----
    #pragma unroll 1
    for (int pass = 0; pass < 4; ++pass) {
        const int lp0 = pass * 8 + wv_ * 2;       // local row base (this wave)
        if (lp0 >= nwork) break;                  // wave-uniform

        float sc[2];
        const float4* xr[2];
        #pragma unroll
        for (int r = 0; r < 2; ++r) {
            const int j = jbeg + lp0 + r;
            const bool valid = (j < jend);
            sc[r] = valid ? 1.f : 0.f;
            const int src = gidx_sh[valid ? j : jbeg];   // jbeg valid (nwork>0)
            xr[r] = reinterpret_cast<const float4*>(x + ((size_t)bat * SS + src) * HH);
        }

        // burst: 8 wave-loads (1KB contiguous each) issued back-to-back
        float4 xq[2][4];                          // [r][i], static-indexed
        #pragma unroll
        for (int i = 0; i < 4; ++i)
            #pragma unroll
            for (int r = 0; r < 2; ++r) xq[r][i] = xr[r][i * 64 + lane];

        float acc[2][LL];
        #pragma unroll
        for (int r = 0; r < 2; ++r)
            #pragma unroll
            for (int l = 0; l < LL; ++l) acc[r][l] = 0.f;

        #pragma unroll
        for (int i = 0; i < 4; ++i) {
            // lane's W sub-block for h-block (i*64+lane): 36 contiguous floats
            float4 wb[9];
            const float* wp = &Wl[(i * 64 + lane) * 36];
            #pragma unroll
            for (int j2 = 0; j2 < 9; ++j2)
                wb[j2] = *reinterpret_cast<const float4*>(wp + j2 * 4);
            const float* wf = reinterpret_cast<const float*>(wb); // wf[dh*9+l]

            #pragma unroll
            for (int l = 0; l < LL; ++l) {
                #pragma unroll
                for (int r = 0; r < 2; ++r) {
                    const float4 xvv = xq[r][i];
                    acc[r][l] += xvv.x * wf[0 * 9 + l] + xvv.y * wf[1 * 9 + l]
                               + xvv.z * wf[2 * 9 + l] + xvv.w * wf[3 * 9 + l];
                }
            }
        }

        // 64-lane reduce, pure DPP: lane 63 ends with each full total
        #pragma unroll
        for (int r = 0; r < 2; ++r)
            #pragma unroll
            for (int l = 0; l < LL; ++l) {
                float v = acc[r][l];
                v = dpp_add<0x111>(v);
                v = dpp_add<0x112>(v);
                v = dpp_add<0x114>(v);
                v = dpp_add<0x118>(v);
                v = dpp_add<0x142>(v);
                v = dpp_add<0x143>(v);
                acc[r][l] = v;
            }

        if (lane == 63) {
            #pragma unroll
            for (int r = 0; r < 2; ++r) {
                float lg[LL];
                float mx = -3.0e38f;
                #pragma unroll
                for (int l = 0; l < LL; ++l) {
                    lg[l] = acc[r][l] * sc[r] + bsh[l];
                    mx = fmaxf(mx, lg[l]);
                }
                float ssum = 0.f;
                #pragma unroll
                for (int l = 0; l < LL; ++l) { lg[l] = __expf(lg[l] - mx); ssum += lg[l]; }
                const float inv = 1.f / ssum;
                #pragma unroll
                for (int l = 0; l < LL; ++l) obuf[(lp0 + r) * LL + l] = lg[l] * inv;
            }
        }
    }

    // softmax(bias) in registers (for pad slice)
    float bs[LL];
    float mxb = -3.0e38f;
    #pragma unroll
    for (int l = 0; l < LL; ++l) { bs[l] = bsh[l]; mxb = fmaxf(mxb, bs[l]); }
    float sb = 0.f;
    #pragma unroll
    for (int l = 0; l < LL; ++l) { bs[l] = __expf(bs[l] - mxb); sb += bs[l]; }
    const float invb = 1.f / sb;

    __syncthreads();                              // obuf complete

    // valid slice: contiguous nwork*9 floats
    const size_t vbase = ((size_t)bat * SS + jbeg) * LL;
    for (int t = tid; t < nwork * LL; t += 256) out[vbase + t] = obuf[t];

    // pad slice: contiguous (pend-pbeg)*9 floats of softmax(bias)
    const size_t pbase = ((size_t)bat * SS + pbeg) * LL;
    const int pn = (pend - pbeg) * LL;
    for (int t = tid; t < pn; t += 256) {
        const int row = t / LL;
        const int l   = t - row * LL;
        out[pbase + t] = bs[l] * invb;
    }
}

extern "C" void kernel_launch(void* const* d_in, const int* in_sizes, int n_in,
                              void* d_out, int out_size, void* d_ws, size_t ws_size,
                              hipStream_t stream) {
    const float* x    = (const float*)d_in[0];   // [B,S,H] f32
    const int*   mask = (const int*)d_in[1];     // [B,S] i32
    const float* W    = (const float*)d_in[2];   // [H,L] f32
    const float* bias = (const float*)d_in[3];   // [L] f32
    float* out = (float*)d_out;                  // [B,S,L] f32

    fused_ner_kernel<<<BB * 16, 256, 0, stream>>>(x, mask, W, bias, out);
}